// Round 8
// baseline (153.561 us; speedup 1.0000x reference)
//
#include <hip/hip_runtime.h>
#include <math.h>

#define INV2PI 0.15915494309189535f

typedef _Float16 f16;
typedef _Float16 f16x8 __attribute__((ext_vector_type(8)));
typedef _Float16 f16x4 __attribute__((ext_vector_type(4)));
typedef float f32x16 __attribute__((ext_vector_type(16)));

#define Z16 {0.f,0.f,0.f,0.f,0.f,0.f,0.f,0.f,0.f,0.f,0.f,0.f,0.f,0.f,0.f,0.f}

// workspace layout in FLOAT units
#define WS_MATS 0        // [2][8][2][16384] f16 (fragment-major) = 262144 floats
#define WS_TABS 262144   // [2][8][2][128] f32 (revolutions)
#define WS_RY1  266240   // [2][14][2] f32
#define WS_XR   266304   // 64*14
#define WS_XR2  267200   // 64*14

// ---- precompute: gate Kron matrices (fp16, MFMA-fragment-major), alpha tables, ry1
__global__ void k_pre(const float* __restrict__ w1, float* __restrict__ ws)
{
    int blk = blockIdx.x, t = threadIdx.x;
    if (blk < 32) {
        // blk = n*16 + (k-2)*2 + side ; side 0 = A (a-bits, wires 6-i), 1 = B (wires 13-i)
        int n = blk >> 4, rem = blk & 15, k = (rem >> 1) + 2, side = rem & 1;
        __shared__ float R[7][2][2];
        if (t < 7) {
            int wire = side ? (13 - t) : (6 - t);
            float th = w1[n*378 + (k-1)*42 + wire*3 + 1];
            float s, c; sincosf(0.5f*th, &s, &c);
            R[t][0][0] = c;  R[t][0][1] = -s;
            R[t][1][0] = s;  R[t][1][1] = c;
        }
        __syncthreads();
        // fragment-major: flat = (tile<<12)|(kk<<9)|(l<<3)|j
        // row = tile*32 + (l&31); col = kk*16 + (l>>5)*8 + j; M[row][col]
        f16* M = (f16*)ws + blk * 16384;
        for (int e = t; e < 16384; e += 256) {
            int tile = e >> 12, kk = (e >> 9) & 7, l = (e >> 3) & 63, j = e & 7;
            int row = tile*32 + (l & 31);
            int col = kk*16 + (l >> 5)*8 + j;
            float v = 1.f;
            #pragma unroll
            for (int bi = 0; bi < 7; ++bi) v *= R[bi][(row>>bi)&1][(col>>bi)&1];
            M[e] = (f16)v;
        }
    } else if (blk == 32) {
        for (int e = t; e < 4096; e += 256) {
            int n = e >> 11, r = e & 2047, k = (r >> 8) + 1;
            int r2 = r & 255, side = r2 >> 7, v = r2 & 127;
            float acc = 0.f;
            #pragma unroll
            for (int bi = 0; bi < 7; ++bi) {
                if ((v >> bi) & 1) {
                    int wire = side ? (13 - bi) : (6 - bi);
                    acc += (w1[n*378 + (k-1)*42 + wire*3 + 2]
                          + w1[n*378 + k*42     + wire*3 + 0]) * INV2PI;
                }
            }
            ws[WS_TABS + ((n*8 + (k-1))*2 + side)*128 + v] = acc;
        }
    } else {
        if (t < 28) {
            int n = t / 14, q = t % 14;
            float th = w1[n*378 + q*3 + 1];
            float s, c; sincosf(0.5f*th, &s, &c);
            ws[WS_RY1 + (n*14 + q)*2 + 0] = c;
            ws[WS_RY1 + (n*14 + q)*2 + 1] = s;
        }
    }
}

// ---- linear_down ----
__global__ void k_down(const float* __restrict__ x, const float* __restrict__ wd,
                       const float* __restrict__ bd, float* __restrict__ xr)
{
    int row  = blockIdx.x;
    int wave = threadIdx.x >> 6;
    int lane = threadIdx.x & 63;
    const float* xrow = x + row * 784;
    for (int f = wave; f < 14; f += 4) {
        const float* wrow = wd + f * 784;
        float s = 0.f;
        for (int j = lane; j < 784; j += 64) s = fmaf(xrow[j], wrow[j], s);
        #pragma unroll
        for (int off = 32; off; off >>= 1) s += __shfl_xor(s, off);
        if (lane == 0) xr[row * 14 + f] = s + bd[f];
    }
}

// ---- circuit: 1024 thr / 16 waves, one 32x32 tile per wave, ETAB diag ----
template<int WHICH>
__global__ __launch_bounds__(1024, 4)
void k_circuit(const f16* __restrict__ matsg, const float* __restrict__ tabsg,
               const float* __restrict__ ry1g, const float* __restrict__ xrin,
               float* __restrict__ xrout, const float* __restrict__ bnw,
               const float* __restrict__ bnb, const float* __restrict__ wu,
               const float* __restrict__ bu)
{
    __shared__ __align__(16) ushort SRe[16384];
    __shared__ __align__(16) ushort SIm[16384];
    __shared__ __align__(16) ushort IRe[16384];
    __shared__ __align__(16) ushort IIm[16384];
    __shared__ float2 ETAB[8][2][128];
    __shared__ float PA[128], PB[128];
    __shared__ float XR[896];
    __shared__ float XROW[14];
    __shared__ float RED[16][15];

    const int row = blockIdx.x, T = threadIdx.x;
    const int w = T >> 6, l = T & 63, lm = l & 31, hb = l >> 5;
    const int tm = w >> 2, tn = w & 3;
    const int mrow = tm*32 + lm, nn = tn*32 + lm;

    for (int i = T; i < 896; i += 1024) XR[i] = xrin[i];
    __syncthreads();
    if (T < 14) {   // BatchNorm (batch stats), output in revolutions
        float mu = 0.f;
        for (int r = 0; r < 64; ++r) mu += XR[r*14 + T];
        mu *= (1.f/64.f);
        float var = 0.f;
        for (int r = 0; r < 64; ++r) { float d = XR[r*14 + T] - mu; var += d*d; }
        var *= (1.f/64.f);
        float xb = (XR[row*14 + T] - mu) * rsqrtf(var + 1e-5f) * bnw[T] + bnb[T];
        XROW[T] = xb * INV2PI;
    }
    __syncthreads();
    for (int e = T; e < 2048; e += 1024) {  // ETAB: e^{2πi·(alpha [+x at k=3,6])}
        int k0 = e >> 8, r2 = e & 255, side = r2 >> 7, v = r2 & 127;
        float val = tabsg[(k0*2 + side)*128 + v];
        if (k0 == 2 || k0 == 5) {
            #pragma unroll
            for (int bi = 0; bi < 7; ++bi)
                if ((v >> bi) & 1) val += XROW[side ? (13-bi) : (6-bi)];
        }
        float fr = __builtin_amdgcn_fractf(val);
        ETAB[k0][side][v] = make_float2(__builtin_amdgcn_cosf(fr),
                                        __builtin_amdgcn_sinf(fr));
    }
    if (T < 256) {   // layer-1 product-state factors
        int side = T >> 7, v = T & 127;
        float p = 1.f;
        #pragma unroll
        for (int bi = 0; bi < 7; ++bi) {
            int wire = side ? (13-bi) : (6-bi);
            p *= ((v >> bi) & 1) ? ry1g[wire*2 + 1] : ry1g[wire*2];
        }
        if (side) PB[v] = p; else PA[v] = p;
    }
    __syncthreads();
    {   // init: S[a][b] = pa*pb * eA[a]*eB[b] * (-1)^{czpar(d,1)}
        int a = T >> 3, b0 = (T & 7) << 4;
        float2 eA = ETAB[0][0][a];
        float pav = PA[a];
        #pragma unroll
        for (int g = 0; g < 2; ++g) {
            f16 hr[8], hm[8];
            #pragma unroll
            for (int u = 0; u < 8; ++u) {
                int b = b0 + g*8 + u;
                int d = (a << 7) | b;
                int rot = ((d >> 1) | (d << 13)) & 16383;
                float2 eB = ETAB[0][1][b];
                float zr = eA.x*eB.x - eA.y*eB.y;
                float zi = eA.x*eB.y + eA.y*eB.x;
                if (__popc(d & rot) & 1) { zr = -zr; zi = -zi; }
                float mg = pav * PB[b];
                hr[u] = (f16)(mg * zr);
                hm[u] = (f16)(mg * zi);
            }
            int hoff = ((a << 7) + b0 + g*8) ^ ((a & 15) << 3);
            f16x8 vr = {hr[0],hr[1],hr[2],hr[3],hr[4],hr[5],hr[6],hr[7]};
            f16x8 vi = {hm[0],hm[1],hm[2],hm[3],hm[4],hm[5],hm[6],hm[7]};
            *(f16x8*)((f16*)SRe + hoff) = vr;
            *(f16x8*)((f16*)SIm + hoff) = vi;
        }
    }
    __syncthreads();

    // prologue: prefetch stage-1 B fragments for k=2 (P=0 -> M1 = side B = idx 1)
    f16x8 Bf[8], Af[8];
    {
        const f16* M1 = matsg + 1 * 16384;
        #pragma unroll
        for (int kk = 0; kk < 8; ++kk)
            Bf[kk] = *(const f16x8*)(M1 + (tn*8 + kk)*512 + l*8);
    }

    #pragma unroll 1
    for (int k = 2; k <= 9; ++k) {
        const int P = k & 1;
        const f16* M2 = matsg + ((k-2)*2 + (P ? 1 : 0)) * 16384;
        // ---- stage 1: I[n][m] = sum_c S[m][c] * M1[n][c] ----
        f32x16 ar = Z16, ai = Z16;
        __builtin_amdgcn_s_setprio(1);
        #pragma unroll
        for (int kk = 0; kk < 8; ++kk) {
            int c  = kk*16 + hb*8;
            int sa = ((mrow << 7) + c) ^ ((mrow & 15) << 3);
            f16x8 Ar = *(const f16x8*)((const f16*)SRe + sa);
            f16x8 Ai = *(const f16x8*)((const f16*)SIm + sa);
            ar = __builtin_amdgcn_mfma_f32_32x32x16_f16(Ar, Bf[kk], ar, 0,0,0);
            ai = __builtin_amdgcn_mfma_f32_32x32x16_f16(Ai, Bf[kk], ai, 0,0,0);
        }
        __builtin_amdgcn_s_setprio(0);
        // prefetch stage-2 A fragments (latency hidden by epilogue+barrier)
        #pragma unroll
        for (int kk = 0; kk < 8; ++kk)
            Af[kk] = *(const f16x8*)(M2 + (tm*8 + kk)*512 + l*8);
        #pragma unroll
        for (int g = 0; g < 4; ++g) {
            int mb = tm*32 + g*8 + hb*4;
            int hoff = ((nn << 7) + mb) ^ ((nn & 15) << 3);
            f16x4 vr = {(f16)ar[g*4],(f16)ar[g*4+1],(f16)ar[g*4+2],(f16)ar[g*4+3]};
            f16x4 vi = {(f16)ai[g*4],(f16)ai[g*4+1],(f16)ai[g*4+2],(f16)ai[g*4+3]};
            *(f16x4*)((f16*)IRe + hoff) = vr;
            *(f16x4*)((f16*)IIm + hoff) = vi;
        }
        __syncthreads();
        // ---- stage 2: S'[n][m'] = sum_c M2[m'][c] * I[n][c] (+ diag) ----
        f32x16 dr = Z16, di = Z16;
        __builtin_amdgcn_s_setprio(1);
        #pragma unroll
        for (int kk = 0; kk < 8; ++kk) {
            int c  = kk*16 + hb*8;
            int s0 = ((nn << 7) + c) ^ ((nn & 15) << 3);
            f16x8 Br = *(const f16x8*)((const f16*)IRe + s0);
            f16x8 Bi = *(const f16x8*)((const f16*)IIm + s0);
            dr = __builtin_amdgcn_mfma_f32_32x32x16_f16(Af[kk], Br, dr, 0,0,0);
            di = __builtin_amdgcn_mfma_f32_32x32x16_f16(Af[kk], Bi, di, 0,0,0);
        }
        __builtin_amdgcn_s_setprio(0);
        if (k < 9) {
            // prefetch next layer's stage-1 B fragments
            {
                const int Pn = (k + 1) & 1;
                const f16* M1n = matsg + ((k-1)*2 + (Pn ? 0 : 1)) * 16384;
                #pragma unroll
                for (int kk = 0; kk < 8; ++kk)
                    Bf[kk] = *(const f16x8*)(M1n + (tn*8 + kk)*512 + l*8);
            }
            float2 eN = ETAB[k-1][P ? 0 : 1][nn];
            const int czr = ((k-1) % 3) + 1;
            #pragma unroll
            for (int g = 0; g < 4; ++g) {
                float prf[4], pif[4];
                #pragma unroll
                for (int u = 0; u < 4; ++u) {
                    int r = g*4 + u;
                    int mloc = (r & 3) + 8*(r >> 2) + 4*hb;
                    int mg = tm*32 + mloc;
                    float2 eM = ETAB[k-1][P ? 1 : 0][mg];
                    int d = P ? ((nn << 7) | mg) : ((mg << 7) | nn);
                    int rot = ((d >> czr) | (d << (14 - czr))) & 16383;
                    float zr = eM.x*eN.x - eM.y*eN.y;
                    float zi = eM.x*eN.y + eM.y*eN.x;
                    if (__popc(d & rot) & 1) { zr = -zr; zi = -zi; }
                    float re = dr[r], im = di[r];
                    prf[u] = re*zr - im*zi;
                    pif[u] = re*zi + im*zr;
                }
                int mb = tm*32 + g*8 + hb*4;
                int hoff = ((nn << 7) + mb) ^ ((nn & 15) << 3);
                f16x4 vr = {(f16)prf[0],(f16)prf[1],(f16)prf[2],(f16)prf[3]};
                f16x4 vi = {(f16)pif[0],(f16)pif[1],(f16)pif[2],(f16)pif[3]};
                *(f16x4*)((f16*)SRe + hoff) = vr;
                *(f16x4*)((f16*)SIm + hoff) = vi;
            }
        } else {   // k=9 (P1: m=b, n=a): measure from fp32 accumulators
            float tot = 0.f;
            float bs[14];
            #pragma unroll
            for (int i = 0; i < 14; ++i) bs[i] = 0.f;
            float tp = 0.f, s0 = 0.f, s1v = 0.f, s3 = 0.f, s4 = 0.f;
            #pragma unroll
            for (int r = 0; r < 16; ++r) {
                float re = dr[r], im = di[r];
                float p = fmaf(re, re, im*im);
                tp += p;
                if (r & 1) s0  += p;
                if (r & 2) s1v += p;
                if (r & 4) s3  += p;
                if (r & 8) s4  += p;
            }
            tot += tp;
            bs[0] += s0; bs[1] += s1v; bs[3] += s3; bs[4] += s4;
            if (hb)     bs[2] += tp;
            if (tm & 1) bs[5] += tp;
            if (tm & 2) bs[6] += tp;
            #pragma unroll
            for (int i = 0; i < 7; ++i)
                if ((nn >> i) & 1) bs[7+i] += tp;
            #pragma unroll
            for (int off = 32; off; off >>= 1) {
                tot += __shfl_xor(tot, off);
                #pragma unroll
                for (int i = 0; i < 14; ++i) bs[i] += __shfl_xor(bs[i], off);
            }
            if (l == 0) {
                #pragma unroll
                for (int i = 0; i < 14; ++i) RED[w][i] = bs[i];
                RED[w][14] = tot;
            }
        }
        __syncthreads();
    }

    if (T < 14) {
        float tt = 0.f, ss = 0.f;
        #pragma unroll
        for (int ww = 0; ww < 16; ++ww) { tt += RED[ww][14]; ss += RED[ww][13 - T]; }
        float val = tt - 2.f * ss;
        XROW[T] = val;
        if (WHICH == 0) xrout[row*14 + T] = val;
    }
    __syncthreads();
    if (WHICH == 1) {   // fused linear_up
        for (int j = T; j < 784; j += 1024) {
            float s = bu[j];
            #pragma unroll
            for (int f = 0; f < 14; ++f) s = fmaf(XROW[f], wu[j*14 + f], s);
            xrout[row*784 + j] = s;
        }
    }
}

extern "C" void kernel_launch(void* const* d_in, const int* in_sizes, int n_in,
                              void* d_out, int out_size, void* d_ws, size_t ws_size,
                              hipStream_t stream)
{
    const float* x  = (const float*)d_in[0];
    const float* wd = (const float*)d_in[1];
    const float* bd = (const float*)d_in[2];
    const float* bw = (const float*)d_in[3];
    const float* bb = (const float*)d_in[4];
    const float* w1 = (const float*)d_in[5];
    const float* wu = (const float*)d_in[6];
    const float* bu = (const float*)d_in[7];
    float* out = (float*)d_out;
    float* ws  = (float*)d_ws;

    hipLaunchKernelGGL(k_pre,  dim3(34), dim3(256), 0, stream, w1, ws);
    hipLaunchKernelGGL(k_down, dim3(64), dim3(256), 0, stream, x, wd, bd, ws + WS_XR);

    const f16* mats0 = (const f16*)ws;
    const f16* mats1 = (const f16*)ws + 262144;
    hipLaunchKernelGGL(k_circuit<0>, dim3(64), dim3(1024), 0, stream,
                       mats0, ws + WS_TABS, ws + WS_RY1,
                       ws + WS_XR, ws + WS_XR2, bw, bb, wu, bu);
    hipLaunchKernelGGL(k_circuit<1>, dim3(64), dim3(1024), 0, stream,
                       mats1, ws + WS_TABS + 2048, ws + WS_RY1 + 28,
                       ws + WS_XR2, out, bw, bb, wu, bu);
}

// Round 9
// 124.319 us; speedup vs baseline: 1.2352x; 1.2352x over previous
//
#include <hip/hip_runtime.h>
#include <math.h>

#define INV2PI 0.15915494309189535f

typedef _Float16 f16;
typedef _Float16 f16x8 __attribute__((ext_vector_type(8)));
typedef _Float16 f16x4 __attribute__((ext_vector_type(4)));
typedef float f32x16 __attribute__((ext_vector_type(16)));

#define Z16 {0.f,0.f,0.f,0.f,0.f,0.f,0.f,0.f,0.f,0.f,0.f,0.f,0.f,0.f,0.f,0.f}

// workspace layout in FLOAT units
#define WS_MATS 0        // [2][8][2][16384] f16 (fragment-major) = 262144 floats
#define WS_TABS 262144   // [2][8][2][128] f32 (revolutions)
#define WS_RY1  266240   // [2][14][2] f32
#define WS_XR   266304   // 64*14
#define WS_XR2  267200   // 64*14

// ---- precompute: gate Kron matrices (fp16, MFMA-fragment-major), alpha tables, ry1
__global__ void k_pre(const float* __restrict__ w1, float* __restrict__ ws)
{
    int blk = blockIdx.x, t = threadIdx.x;
    if (blk < 32) {
        // blk = n*16 + (k-2)*2 + side ; side 0 = A (a-bits, wires 6-i), 1 = B (wires 13-i)
        int n = blk >> 4, rem = blk & 15, k = (rem >> 1) + 2, side = rem & 1;
        __shared__ float R[7][2][2];
        if (t < 7) {
            int wire = side ? (13 - t) : (6 - t);
            float th = w1[n*378 + (k-1)*42 + wire*3 + 1];
            float s, c; sincosf(0.5f*th, &s, &c);
            R[t][0][0] = c;  R[t][0][1] = -s;
            R[t][1][0] = s;  R[t][1][1] = c;
        }
        __syncthreads();
        // fragment-major: flat = (tile<<12)|(kk<<9)|(l<<3)|j
        // row = tile*32 + (l&31); col = kk*16 + (l>>5)*8 + j; M[row][col]
        f16* M = (f16*)ws + blk * 16384;
        for (int e = t; e < 16384; e += 256) {
            int tile = e >> 12, kk = (e >> 9) & 7, l = (e >> 3) & 63, j = e & 7;
            int row = tile*32 + (l & 31);
            int col = kk*16 + (l >> 5)*8 + j;
            float v = 1.f;
            #pragma unroll
            for (int bi = 0; bi < 7; ++bi) v *= R[bi][(row>>bi)&1][(col>>bi)&1];
            M[e] = (f16)v;
        }
    } else if (blk == 32) {
        for (int e = t; e < 4096; e += 256) {
            int n = e >> 11, r = e & 2047, k = (r >> 8) + 1;
            int r2 = r & 255, side = r2 >> 7, v = r2 & 127;
            float acc = 0.f;
            #pragma unroll
            for (int bi = 0; bi < 7; ++bi) {
                if ((v >> bi) & 1) {
                    int wire = side ? (13 - bi) : (6 - bi);
                    acc += (w1[n*378 + (k-1)*42 + wire*3 + 2]
                          + w1[n*378 + k*42     + wire*3 + 0]) * INV2PI;
                }
            }
            ws[WS_TABS + ((n*8 + (k-1))*2 + side)*128 + v] = acc;
        }
    } else {
        if (t < 28) {
            int n = t / 14, q = t % 14;
            float th = w1[n*378 + q*3 + 1];
            float s, c; sincosf(0.5f*th, &s, &c);
            ws[WS_RY1 + (n*14 + q)*2 + 0] = c;
            ws[WS_RY1 + (n*14 + q)*2 + 1] = s;
        }
    }
}

// ---- linear_down ----
__global__ void k_down(const float* __restrict__ x, const float* __restrict__ wd,
                       const float* __restrict__ bd, float* __restrict__ xr)
{
    int row  = blockIdx.x;
    int wave = threadIdx.x >> 6;
    int lane = threadIdx.x & 63;
    const float* xrow = x + row * 784;
    for (int f = wave; f < 14; f += 4) {
        const float* wrow = wd + f * 784;
        float s = 0.f;
        for (int j = lane; j < 784; j += 64) s = fmaf(xrow[j], wrow[j], s);
        #pragma unroll
        for (int off = 32; off; off >>= 1) s += __shfl_xor(s, off);
        if (lane == 0) xr[row * 14 + f] = s + bd[f];
    }
}

// ---- circuit: 1024 thr / 16 waves, one 32x32 tile per wave, ETAB diag ----
template<int WHICH>
__global__ __launch_bounds__(1024, 4)
void k_circuit(const f16* __restrict__ matsg, const float* __restrict__ tabsg,
               const float* __restrict__ ry1g, const float* __restrict__ xrin,
               float* __restrict__ xrout, const float* __restrict__ bnw,
               const float* __restrict__ bnb, const float* __restrict__ wu,
               const float* __restrict__ bu)
{
    __shared__ __align__(16) ushort SRe[16384];
    __shared__ __align__(16) ushort SIm[16384];
    __shared__ __align__(16) ushort IRe[16384];
    __shared__ __align__(16) ushort IIm[16384];
    __shared__ float2 ETAB[8][2][128];
    __shared__ float PA[128], PB[128];
    __shared__ float XR[896];
    __shared__ float XROW[14];
    __shared__ float RED[16][15];

    const int row = blockIdx.x, T = threadIdx.x;
    const int w = T >> 6, l = T & 63, lm = l & 31, hb = l >> 5;
    const int tm = w >> 2, tn = w & 3;
    const int mrow = tm*32 + lm, nn = tn*32 + lm;

    for (int i = T; i < 896; i += 1024) XR[i] = xrin[i];
    __syncthreads();
    if (T < 14) {   // BatchNorm (batch stats), output in revolutions
        float mu = 0.f;
        for (int r = 0; r < 64; ++r) mu += XR[r*14 + T];
        mu *= (1.f/64.f);
        float var = 0.f;
        for (int r = 0; r < 64; ++r) { float d = XR[r*14 + T] - mu; var += d*d; }
        var *= (1.f/64.f);
        float xb = (XR[row*14 + T] - mu) * rsqrtf(var + 1e-5f) * bnw[T] + bnb[T];
        XROW[T] = xb * INV2PI;
    }
    __syncthreads();
    for (int e = T; e < 2048; e += 1024) {  // ETAB: e^{2πi·(alpha [+x at k=3,6])}
        int k0 = e >> 8, r2 = e & 255, side = r2 >> 7, v = r2 & 127;
        float val = tabsg[(k0*2 + side)*128 + v];
        if (k0 == 2 || k0 == 5) {
            #pragma unroll
            for (int bi = 0; bi < 7; ++bi)
                if ((v >> bi) & 1) val += XROW[side ? (13-bi) : (6-bi)];
        }
        float fr = __builtin_amdgcn_fractf(val);
        ETAB[k0][side][v] = make_float2(__builtin_amdgcn_cosf(fr),
                                        __builtin_amdgcn_sinf(fr));
    }
    if (T < 256) {   // layer-1 product-state factors
        int side = T >> 7, v = T & 127;
        float p = 1.f;
        #pragma unroll
        for (int bi = 0; bi < 7; ++bi) {
            int wire = side ? (13-bi) : (6-bi);
            p *= ((v >> bi) & 1) ? ry1g[wire*2 + 1] : ry1g[wire*2];
        }
        if (side) PB[v] = p; else PA[v] = p;
    }
    __syncthreads();
    {   // init: S[a][b] = pa*pb * eA[a]*eB[b] * (-1)^{czpar(d,1)}
        int a = T >> 3, b0 = (T & 7) << 4;
        float2 eA = ETAB[0][0][a];
        float pav = PA[a];
        #pragma unroll
        for (int g = 0; g < 2; ++g) {
            f16 hr[8], hm[8];
            #pragma unroll
            for (int u = 0; u < 8; ++u) {
                int b = b0 + g*8 + u;
                int d = (a << 7) | b;
                int rot = ((d >> 1) | (d << 13)) & 16383;
                float2 eB = ETAB[0][1][b];
                float zr = eA.x*eB.x - eA.y*eB.y;
                float zi = eA.x*eB.y + eA.y*eB.x;
                if (__popc(d & rot) & 1) { zr = -zr; zi = -zi; }
                float mg = pav * PB[b];
                hr[u] = (f16)(mg * zr);
                hm[u] = (f16)(mg * zi);
            }
            int hoff = ((a << 7) + b0 + g*8) ^ ((a & 15) << 3);
            f16x8 vr = {hr[0],hr[1],hr[2],hr[3],hr[4],hr[5],hr[6],hr[7]};
            f16x8 vi = {hm[0],hm[1],hm[2],hm[3],hm[4],hm[5],hm[6],hm[7]};
            *(f16x8*)((f16*)SRe + hoff) = vr;
            *(f16x8*)((f16*)SIm + hoff) = vi;
        }
    }
    __syncthreads();

    #pragma unroll 1
    for (int k = 2; k <= 9; ++k) {
        const int P = k & 1;
        const f16* M1 = matsg + ((k-2)*2 + (P ? 0 : 1)) * 16384;
        const f16* M2 = matsg + ((k-2)*2 + (P ? 1 : 0)) * 16384;
        // ---- stage 1: I[n][m] = sum_c S[m][c] * M1[n][c] ----
        f32x16 ar = Z16, ai = Z16;
        #pragma unroll
        for (int kk = 0; kk < 8; ++kk) {
            f16x8 B = *(const f16x8*)(M1 + (tn*8 + kk)*512 + l*8);
            int c  = kk*16 + hb*8;
            int sa = ((mrow << 7) + c) ^ ((mrow & 15) << 3);
            f16x8 Ar = *(const f16x8*)((const f16*)SRe + sa);
            f16x8 Ai = *(const f16x8*)((const f16*)SIm + sa);
            ar = __builtin_amdgcn_mfma_f32_32x32x16_f16(Ar, B, ar, 0,0,0);
            ai = __builtin_amdgcn_mfma_f32_32x32x16_f16(Ai, B, ai, 0,0,0);
        }
        #pragma unroll
        for (int g = 0; g < 4; ++g) {
            int mb = tm*32 + g*8 + hb*4;
            int hoff = ((nn << 7) + mb) ^ ((nn & 15) << 3);
            f16x4 vr = {(f16)ar[g*4],(f16)ar[g*4+1],(f16)ar[g*4+2],(f16)ar[g*4+3]};
            f16x4 vi = {(f16)ai[g*4],(f16)ai[g*4+1],(f16)ai[g*4+2],(f16)ai[g*4+3]};
            *(f16x4*)((f16*)IRe + hoff) = vr;
            *(f16x4*)((f16*)IIm + hoff) = vi;
        }
        __syncthreads();
        // ---- stage 2: S'[n][m'] = sum_c M2[m'][c] * I[n][c] (+ diag) ----
        f32x16 dr = Z16, di = Z16;
        #pragma unroll
        for (int kk = 0; kk < 8; ++kk) {
            f16x8 A = *(const f16x8*)(M2 + (tm*8 + kk)*512 + l*8);
            int c  = kk*16 + hb*8;
            int s0 = ((nn << 7) + c) ^ ((nn & 15) << 3);
            f16x8 Br = *(const f16x8*)((const f16*)IRe + s0);
            f16x8 Bi = *(const f16x8*)((const f16*)IIm + s0);
            dr = __builtin_amdgcn_mfma_f32_32x32x16_f16(A, Br, dr, 0,0,0);
            di = __builtin_amdgcn_mfma_f32_32x32x16_f16(A, Bi, di, 0,0,0);
        }
        if (k < 9) {
            float2 eN = ETAB[k-1][P ? 0 : 1][nn];
            const int czr = ((k-1) % 3) + 1;
            #pragma unroll
            for (int g = 0; g < 4; ++g) {
                float prf[4], pif[4];
                #pragma unroll
                for (int u = 0; u < 4; ++u) {
                    int r = g*4 + u;
                    int mloc = (r & 3) + 8*(r >> 2) + 4*hb;
                    int mg = tm*32 + mloc;
                    float2 eM = ETAB[k-1][P ? 1 : 0][mg];
                    int d = P ? ((nn << 7) | mg) : ((mg << 7) | nn);
                    int rot = ((d >> czr) | (d << (14 - czr))) & 16383;
                    float zr = eM.x*eN.x - eM.y*eN.y;
                    float zi = eM.x*eN.y + eM.y*eN.x;
                    if (__popc(d & rot) & 1) { zr = -zr; zi = -zi; }
                    float re = dr[r], im = di[r];
                    prf[u] = re*zr - im*zi;
                    pif[u] = re*zi + im*zr;
                }
                int mb = tm*32 + g*8 + hb*4;
                int hoff = ((nn << 7) + mb) ^ ((nn & 15) << 3);
                f16x4 vr = {(f16)prf[0],(f16)prf[1],(f16)prf[2],(f16)prf[3]};
                f16x4 vi = {(f16)pif[0],(f16)pif[1],(f16)pif[2],(f16)pif[3]};
                *(f16x4*)((f16*)SRe + hoff) = vr;
                *(f16x4*)((f16*)SIm + hoff) = vi;
            }
        } else {   // k=9 (P1: m=b, n=a): measure from fp32 accumulators
            float tot = 0.f;
            float bs[14];
            #pragma unroll
            for (int i = 0; i < 14; ++i) bs[i] = 0.f;
            float tp = 0.f, s0 = 0.f, s1v = 0.f, s3 = 0.f, s4 = 0.f;
            #pragma unroll
            for (int r = 0; r < 16; ++r) {
                float re = dr[r], im = di[r];
                float p = fmaf(re, re, im*im);
                tp += p;
                if (r & 1) s0  += p;
                if (r & 2) s1v += p;
                if (r & 4) s3  += p;
                if (r & 8) s4  += p;
            }
            tot += tp;
            bs[0] += s0; bs[1] += s1v; bs[3] += s3; bs[4] += s4;
            if (hb)     bs[2] += tp;
            if (tm & 1) bs[5] += tp;
            if (tm & 2) bs[6] += tp;
            #pragma unroll
            for (int i = 0; i < 7; ++i)
                if ((nn >> i) & 1) bs[7+i] += tp;
            #pragma unroll
            for (int off = 32; off; off >>= 1) {
                tot += __shfl_xor(tot, off);
                #pragma unroll
                for (int i = 0; i < 14; ++i) bs[i] += __shfl_xor(bs[i], off);
            }
            if (l == 0) {
                #pragma unroll
                for (int i = 0; i < 14; ++i) RED[w][i] = bs[i];
                RED[w][14] = tot;
            }
        }
        __syncthreads();
    }

    if (T < 14) {
        float tt = 0.f, ss = 0.f;
        #pragma unroll
        for (int ww = 0; ww < 16; ++ww) { tt += RED[ww][14]; ss += RED[ww][13 - T]; }
        float val = tt - 2.f * ss;
        XROW[T] = val;
        if (WHICH == 0) xrout[row*14 + T] = val;
    }
    __syncthreads();
    if (WHICH == 1) {   // fused linear_up
        for (int j = T; j < 784; j += 1024) {
            float s = bu[j];
            #pragma unroll
            for (int f = 0; f < 14; ++f) s = fmaf(XROW[f], wu[j*14 + f], s);
            xrout[row*784 + j] = s;
        }
    }
}

extern "C" void kernel_launch(void* const* d_in, const int* in_sizes, int n_in,
                              void* d_out, int out_size, void* d_ws, size_t ws_size,
                              hipStream_t stream)
{
    const float* x  = (const float*)d_in[0];
    const float* wd = (const float*)d_in[1];
    const float* bd = (const float*)d_in[2];
    const float* bw = (const float*)d_in[3];
    const float* bb = (const float*)d_in[4];
    const float* w1 = (const float*)d_in[5];
    const float* wu = (const float*)d_in[6];
    const float* bu = (const float*)d_in[7];
    float* out = (float*)d_out;
    float* ws  = (float*)d_ws;

    hipLaunchKernelGGL(k_pre,  dim3(34), dim3(256), 0, stream, w1, ws);
    hipLaunchKernelGGL(k_down, dim3(64), dim3(256), 0, stream, x, wd, bd, ws + WS_XR);

    const f16* mats0 = (const f16*)ws;
    const f16* mats1 = (const f16*)ws + 262144;
    hipLaunchKernelGGL(k_circuit<0>, dim3(64), dim3(1024), 0, stream,
                       mats0, ws + WS_TABS, ws + WS_RY1,
                       ws + WS_XR, ws + WS_XR2, bw, bb, wu, bu);
    hipLaunchKernelGGL(k_circuit<1>, dim3(64), dim3(1024), 0, stream,
                       mats1, ws + WS_TABS + 2048, ws + WS_RY1 + 28,
                       ws + WS_XR2, out, bw, bb, wu, bu);
}